// Round 1
// baseline (87.792 us; speedup 1.0000x reference)
//
#include <hip/hip_runtime.h>

#define K      5
#define C      3
#define FC     75        // K*K*C floats per pixel
#define NPIX   256       // pixels per block (= threads per block)
#define HH     512
#define WW     512

// LDS chunk: 256 pixels * 75 floats = 19200 floats = 76800 bytes
// float4 view: 4800 float4 = 18*256 + 192  ->  18 full iters + 3 waves

__global__ __launch_bounds__(256, 2)
void convolve_kernel(const float* __restrict__ img,
                     const float* __restrict__ filts,
                     float* __restrict__ out)
{
    __shared__ float sf[NPIX * FC];

    const int tid  = threadIdx.x;
    const int lane = tid & 63;
    const int wave = tid >> 6;

    const size_t block0 = (size_t)blockIdx.x * NPIX;       // first pixel of block
    const float* fsrc   = filts + block0 * FC;             // 16B-aligned (76800*blockIdx)

    // ---- stage filts chunk into LDS, fully coalesced, direct-to-LDS ----
    {
        const int wbase = wave * 64;                       // wave-uniform float4 index part
        #pragma unroll
        for (int i = 0; i < 18; ++i) {
            const int f4 = i * 256 + wbase;                // wave-uniform
            __builtin_amdgcn_global_load_lds(
                (const __attribute__((address_space(1))) void*)(fsrc + (size_t)(f4 + lane) * 4),
                (__attribute__((address_space(3))) void*)(sf + (size_t)f4 * 4),
                16, 0, 0);
        }
        if (wave < 3) {                                    // tail: 192 float4 = 3 full waves
            const int f4 = 18 * 256 + wbase;
            __builtin_amdgcn_global_load_lds(
                (const __attribute__((address_space(1))) void*)(fsrc + (size_t)(f4 + lane) * 4),
                (__attribute__((address_space(3))) void*)(sf + (size_t)f4 * 4),
                16, 0, 0);
        }
    }
    asm volatile("s_waitcnt vmcnt(0)" ::: "memory");
    __syncthreads();

    // ---- compute: one pixel per thread ----
    const int p  = (int)block0 + tid;
    const int b  = p >> 18;                 // / (512*512)
    const int hw = p & ((1 << 18) - 1);
    const int h  = hw >> 9;
    const int w  = hw & 511;

    const float* fp   = sf + tid * FC;
    const float* imgb = img + (size_t)b * (HH * (size_t)WW * C);

    float acc = 0.0f;
    #pragma unroll
    for (int di = 0; di < K; ++di) {
        const int hh = h + di - 2;
        if ((unsigned)hh < (unsigned)HH) {
            const float* row = imgb + (size_t)hh * (WW * C);
            #pragma unroll
            for (int dj = 0; dj < K; ++dj) {
                const int ww = w + dj - 2;
                if ((unsigned)ww < (unsigned)WW) {
                    const float* px = row + ww * C;
                    const int fo = (di * K + dj) * C;
                    acc += px[0] * fp[fo + 0];
                    acc += px[1] * fp[fo + 1];
                    acc += px[2] * fp[fo + 2];
                }
            }
        }
    }
    out[p] = acc;
}

extern "C" void kernel_launch(void* const* d_in, const int* in_sizes, int n_in,
                              void* d_out, int out_size, void* d_ws, size_t ws_size,
                              hipStream_t stream)
{
    const float* img   = (const float*)d_in[0];   // [4,512,512,3] f32
    const float* filts = (const float*)d_in[1];   // [4,512,512,75] f32
    float* out         = (float*)d_out;           // [4,512,512] f32

    const int npix   = out_size;                  // 1,048,576
    const int blocks = npix / NPIX;               // 4096

    convolve_kernel<<<blocks, NPIX, 0, stream>>>(img, filts, out);
}